// Round 4
// baseline (149.938 us; speedup 1.0000x reference)
//
#include <hip/hip_runtime.h>
#include <hip/hip_bf16.h>

// LinearStitcher, round 4: wave-autonomous streaming pipeline, zero barriers.
// x: [16384, 4096] f32, W: [16,128,256] f32, b: [16,128] f32.
// out[:, a*128+c] = sum_k x[:, a*256+k]*W[a,c,k] + b[a,c];  out[:, 2048:] = 0.
//
// Per wave: 32 rows x 128 ch of one area. x staged fp32 via global_load_lds
// (16B) into wave-private triple-buffered LDS (3 x 4KB), global source
// PRE-SWIZZLED (g ^= row&7) so linear LDS writes give conflict-free b128
// fragment reads. W prepacked to bf16 B-fragments (L2-resident), prefetched
// 1 chunk ahead into regs. Counted s_waitcnt vmcnt(16) per chunk; stages keep
// a 2-chunk lead and are never drained. No __syncthreads in the whole kernel.

typedef __attribute__((ext_vector_type(8))) short bf16x8;
typedef __attribute__((ext_vector_type(16))) float f32x16;

#define GLOBAL_AS __attribute__((address_space(1)))
#define LDS_AS    __attribute__((address_space(3)))

static constexpr int NX   = 4096;
static constexpr int OW   = 4096;
static constexpr int KDIM = 256;
static constexpr int CCH  = 128;

// P[a][ks(16)][n(4)][lane(64)] : 16B slot, exact 32x32x16 B-fragment layout
__global__ __launch_bounds__(256)
void prep_w(const float* __restrict__ W, __hip_bfloat16* __restrict__ P) {
    const int t = blockIdx.x * 256 + threadIdx.x;     // 64 blocks
    for (int s = t; s < 65536; s += 16384) {
        const int a  = s >> 12;
        const int w  = s & 4095;
        const int ks = w >> 8;
        const int n  = (w >> 6) & 3;
        const int l  = w & 63;
        const int ch = n * 32 + (l & 31);
        const int k0 = ks * 16 + (l >> 5) * 8;
        const float* src = W + ((long)a * CCH + ch) * KDIM + k0;
        const float4 w0 = *(const float4*)(src);
        const float4 w1 = *(const float4*)(src + 4);
        union { bf16x8 v; __hip_bfloat162 h[4]; } pw;
        pw.h[0] = __float22bfloat162_rn(make_float2(w0.x, w0.y));
        pw.h[1] = __float22bfloat162_rn(make_float2(w0.z, w0.w));
        pw.h[2] = __float22bfloat162_rn(make_float2(w1.x, w1.y));
        pw.h[3] = __float22bfloat162_rn(make_float2(w1.z, w1.w));
        *(bf16x8*)((char*)P + ((long)s << 4)) = pw.v;
    }
}

__global__ __launch_bounds__(256, 3)
void stitch_kernel(const float* __restrict__ x,
                   const __hip_bfloat16* __restrict__ Pw,
                   const float* __restrict__ bias,
                   float* __restrict__ out) {
    const int tid  = threadIdx.x;
    const int lane = tid & 63;
    const int wid  = tid >> 6;
    const int area = blockIdx.x >> 7;
    const int rt   = blockIdx.x & 127;
    const int rowbase = rt * 128 + wid * 32;          // wave's 32 rows

    __shared__ char sb[3][4][4096];                   // [buf][wave][32 rows x 32 k f32]

    // staging source (pre-swizzled): lane covers row (lane>>3), 16B group
    // glog = (lane&7) ^ (row&7); instr i adds 8 rows; chunk c adds 32 k.
    const int srow = lane >> 3;
    const int glog = (lane & 7) ^ (srow & 7);
    const float* gsrc = x + (long)(rowbase + srow) * NX + area * KDIM + glog * 4;

    const bf16x8* bpa = (const bf16x8*)Pw + (long)area * 4096 + lane;

    f32x16 acc[4];
#pragma unroll
    for (int n = 0; n < 4; ++n)
#pragma unroll
        for (int r = 0; r < 16; ++r) acc[n][r] = 0.f;

    bf16x8 Breg[2][8];

#define STAGE(c, buf)                                                          \
    {                                                                          \
        char* lp_ = &sb[buf][wid][0];                                          \
        _Pragma("unroll")                                                      \
        for (int i_ = 0; i_ < 4; ++i_) {                                       \
            __builtin_amdgcn_global_load_lds(                                  \
                (const GLOBAL_AS void*)(gsrc + (long)(8 * i_) * NX + (c) * 32),\
                (LDS_AS void*)(lp_ + i_ * 1024), 16, 0, 0);                    \
        }                                                                      \
    }

#define LOADB(cs, set)                                                         \
    {                                                                          \
        _Pragma("unroll")                                                      \
        for (int j_ = 0; j_ < 8; ++j_)                                         \
            Breg[set][j_] = bpa[(cs) * 512 + (j_ >> 2) * 256 + (j_ & 3) * 64]; \
    }

    // prologue: S0, B0, S1  (issue order defines the vmcnt queue)
    STAGE(0, 0);
    LOADB(0, 0);
    STAGE(1, 1);

    const int row = lane & 31;
    const int kh  = lane >> 5;
    const int rx7 = row & 7;

#pragma unroll
    for (int c = 0; c < 8; ++c) {
        const int cn = (c + 1 > 7) ? 7 : c + 1;       // clamped (dummy) indices
        const int cs = (c + 2 > 7) ? 7 : c + 2;
        LOADB(cn, (c + 1) & 1);                       // B_{c+1}: 8 loads
        STAGE(cs, (c + 2) % 3);                       // S_{c+2}: 4 loads
        // queue: S_c(4), B_c(8), S_{c+1}(4), B_{c+1}(8), S_{c+2}(4) = 28
        // retire S_c + B_c (12 oldest) -> wait to 16; stages keep 2-chunk lead
        asm volatile("s_waitcnt vmcnt(16)" ::: "memory");
        __builtin_amdgcn_sched_barrier(0);

        const char* lb = &sb[c % 3][wid][0];
#pragma unroll
        for (int ks = 0; ks < 2; ++ks) {
            const int G0 = ks * 4 + kh * 2;
            const float4 r0 = *(const float4*)(lb + (row << 7) + ((G0 ^ rx7) << 4));
            const float4 r1 = *(const float4*)(lb + (row << 7) + (((G0 + 1) ^ rx7) << 4));
            union { bf16x8 v; __hip_bfloat162 h[4]; } aw;
            aw.h[0] = __float22bfloat162_rn(make_float2(r0.x, r0.y));
            aw.h[1] = __float22bfloat162_rn(make_float2(r0.z, r0.w));
            aw.h[2] = __float22bfloat162_rn(make_float2(r1.x, r1.y));
            aw.h[3] = __float22bfloat162_rn(make_float2(r1.z, r1.w));
            acc[0] = __builtin_amdgcn_mfma_f32_32x32x16_bf16(aw.v, Breg[c & 1][ks * 4 + 0], acc[0], 0, 0, 0);
            acc[1] = __builtin_amdgcn_mfma_f32_32x32x16_bf16(aw.v, Breg[c & 1][ks * 4 + 1], acc[1], 0, 0, 0);
            acc[2] = __builtin_amdgcn_mfma_f32_32x32x16_bf16(aw.v, Breg[c & 1][ks * 4 + 2], acc[2], 0, 0, 0);
            acc[3] = __builtin_amdgcn_mfma_f32_32x32x16_bf16(aw.v, Breg[c & 1][ks * 4 + 3], acc[3], 0, 0, 0);
        }
    }
#undef STAGE
#undef LOADB

    // epilogue: C/D layout col = lane&31, row = (reg&3) + 8*(reg>>2) + 4*(lane>>5)
    float bv[4];
#pragma unroll
    for (int n = 0; n < 4; ++n)
        bv[n] = bias[area * CCH + n * 32 + row];

    const long rb = rowbase + 4 * kh;
#pragma unroll
    for (int n = 0; n < 4; ++n) {
        const int gcol = area * CCH + n * 32 + row;
#pragma unroll
        for (int r = 0; r < 16; ++r) {
            const long grow = rb + (r & 3) + ((r >> 2) << 3);
            out[grow * OW + gcol] = acc[n][r] + bv[n];
        }
    }

    // zero mirror half: rows rt*128..+128, cols 2048+area*128..+128 (block-wide)
    float4* o4 = (float4*)(out + (long)rt * 128 * OW + 2048 + area * CCH);
    const int zc = tid & 31;
    const int zr = tid >> 5;
    const float4 z = {0.f, 0.f, 0.f, 0.f};
#pragma unroll
    for (int i = 0; i < 16; ++i)
        o4[(long)(zr + (i << 3)) * (OW / 4) + zc] = z;
}

extern "C" void kernel_launch(void* const* d_in, const int* in_sizes, int n_in,
                              void* d_out, int out_size, void* d_ws, size_t ws_size,
                              hipStream_t stream) {
    const float* x    = (const float*)d_in[0];
    const float* W    = (const float*)d_in[1];
    const float* bias = (const float*)d_in[2];
    float* out = (float*)d_out;
    __hip_bfloat16* P = (__hip_bfloat16*)d_ws;   // 1 MB packed W fragments

    prep_w<<<64, 256, 0, stream>>>(W, P);
    stitch_kernel<<<2048, 256, 0, stream>>>(x, P, bias, out);
}

// Round 5
// 139.146 us; speedup vs baseline: 1.0776x; 1.0776x over previous
//
#include <hip/hip_runtime.h>
#include <hip/hip_bf16.h>

// LinearStitcher, round 5: fully-contiguous x streaming.
// x: [16384, 4096] f32, W: [16,128,256] f32, b: [16,128] f32.
// out[:, a*128+c] = sum_k x[:, a*256+k]*W[a,c,k] + b[a,c];  out[:, 2048:] = 0.
//
// Hypothesis under test: prior rounds' 1KB-per-16KB-stride x reads thrash DRAM
// pages (all pipes idle at 0.9-2.6 TB/s). Here each block owns 32 FULL rows and
// processes them in 4 phases of 1024 cols (4 areas each): staging reads are
// 4KB-contiguous per instruction, each block streams 512KB of x exactly once.
// W prepacked to bf16 B-fragments in d_ws (L2-resident). 512 blocks = 2/CU.

typedef __attribute__((ext_vector_type(8))) short bf16x8;
typedef __attribute__((ext_vector_type(16))) float f32x16;

static constexpr int NX   = 4096;
static constexpr int OW   = 4096;
static constexpr int KDIM = 256;
static constexpr int CCH  = 128;

// P[a][ks(16)][n(4)][lane(64)] : 16B slot, exact 32x32x16 B-fragment layout
__global__ __launch_bounds__(256)
void prep_w(const float* __restrict__ W, __hip_bfloat16* __restrict__ P) {
    const int t = blockIdx.x * 256 + threadIdx.x;     // 64 blocks
    for (int s = t; s < 65536; s += 16384) {
        const int a  = s >> 12;
        const int w  = s & 4095;
        const int ks = w >> 8;
        const int n  = (w >> 6) & 3;
        const int l  = w & 63;
        const int ch = n * 32 + (l & 31);
        const int k0 = ks * 16 + (l >> 5) * 8;
        const float* src = W + ((long)a * CCH + ch) * KDIM + k0;
        const float4 w0 = *(const float4*)(src);
        const float4 w1 = *(const float4*)(src + 4);
        union { bf16x8 v; __hip_bfloat162 h[4]; } pw;
        pw.h[0] = __float22bfloat162_rn(make_float2(w0.x, w0.y));
        pw.h[1] = __float22bfloat162_rn(make_float2(w0.z, w0.w));
        pw.h[2] = __float22bfloat162_rn(make_float2(w1.x, w1.y));
        pw.h[3] = __float22bfloat162_rn(make_float2(w1.z, w1.w));
        *(bf16x8*)((char*)P + ((long)s << 4)) = pw.v;
    }
}

__global__ __launch_bounds__(256, 2)
void stitch_kernel(const float* __restrict__ x,
                   const __hip_bfloat16* __restrict__ Pw,
                   const float* __restrict__ bias,
                   float* __restrict__ out) {
    const int tid  = threadIdx.x;
    const int lane = tid & 63;
    const int wid  = tid >> 6;
    const int rowbase = blockIdx.x * 32;              // 512 blocks x 32 rows

    // bf16 panel: [32 rows][1024 cols], 2KB/row, XOR-swizzled 16B granules.
    __shared__ char pan[32 * 2048];                   // 64 KB

    // zero mirror half first: rows rowbase..+32, cols 2048..4096 (contiguous 4KB bursts)
    {
        float4* o4 = (float4*)out;
        const float4 z = {0.f, 0.f, 0.f, 0.f};
#pragma unroll 4
        for (int i = 0; i < 64; ++i) {
            const int s = i * 256 + tid;              // 32 rows * 512 groups
            const int r = s >> 9, g = s & 511;
            o4[(long)(rowbase + r) * (OW / 4) + 512 + g] = z;
        }
    }

    const int row = lane & 31;
    const int kh  = lane >> 5;
    const int g16 = tid >> 1;                         // staging 16B-granule index
    const int ghalf = (tid & 1) << 3;

    for (int p = 0; p < 4; ++p) {
        // ---- stage 32 rows x 1024 cols (4KB contiguous per instruction) ----
        {
            const float* src = x + (long)rowbase * NX + p * 1024 + (tid << 2);
#pragma unroll 8
            for (int r = 0; r < 32; ++r) {
                const float4 v = *(const float4*)(src + (long)r * NX);
                union { unsigned long long u; __hip_bfloat162 h[2]; } pw;
                pw.h[0] = __float22bfloat162_rn(make_float2(v.x, v.y));
                pw.h[1] = __float22bfloat162_rn(make_float2(v.z, v.w));
                const int off = (r << 11) + (((g16 ^ (r & 7)) << 4)) + ghalf;
                *(unsigned long long*)(&pan[off]) = pw.u;
            }
        }
        __syncthreads();

        // ---- compute: wave `wid` does area p*4+wid over k=256 ----
        const int area = p * 4 + wid;
        const bf16x8* bpa = (const bf16x8*)Pw + (long)area * 4096 + lane;

        f32x16 acc[4];
#pragma unroll
        for (int n = 0; n < 4; ++n)
#pragma unroll
            for (int r = 0; r < 16; ++r) acc[n][r] = 0.f;

#pragma unroll
        for (int ks = 0; ks < 16; ++ks) {
            const int g = wid * 32 + ks * 2 + kh;     // A-frag granule in panel row
            const bf16x8 af = *(const bf16x8*)(&pan[(row << 11) + ((g ^ (row & 7)) << 4)]);
            const bf16x8* bn = bpa + ks * 256;
            const bf16x8 b0 = bn[0], b1 = bn[64], b2 = bn[128], b3 = bn[192];
            acc[0] = __builtin_amdgcn_mfma_f32_32x32x16_bf16(af, b0, acc[0], 0, 0, 0);
            acc[1] = __builtin_amdgcn_mfma_f32_32x32x16_bf16(af, b1, acc[1], 0, 0, 0);
            acc[2] = __builtin_amdgcn_mfma_f32_32x32x16_bf16(af, b2, acc[2], 0, 0, 0);
            acc[3] = __builtin_amdgcn_mfma_f32_32x32x16_bf16(af, b3, acc[3], 0, 0, 0);
        }

        // ---- epilogue: C/D col = lane&31, row = (reg&3) + 8*(reg>>2) + 4*(lane>>5)
        float bv[4];
#pragma unroll
        for (int n = 0; n < 4; ++n)
            bv[n] = bias[area * CCH + n * 32 + row];

        const long rb = rowbase + 4 * kh;
#pragma unroll
        for (int n = 0; n < 4; ++n) {
            const int gcol = area * CCH + n * 32 + row;
#pragma unroll
            for (int r = 0; r < 16; ++r) {
                const long grow = rb + (r & 3) + ((r >> 2) << 3);
                out[grow * OW + gcol] = acc[n][r] + bv[n];
            }
        }
        __syncthreads();   // panel reuse: all LDS reads done before next stage
    }
}

extern "C" void kernel_launch(void* const* d_in, const int* in_sizes, int n_in,
                              void* d_out, int out_size, void* d_ws, size_t ws_size,
                              hipStream_t stream) {
    const float* x    = (const float*)d_in[0];
    const float* W    = (const float*)d_in[1];
    const float* bias = (const float*)d_in[2];
    float* out = (float*)d_out;
    __hip_bfloat16* P = (__hip_bfloat16*)d_ws;   // 1 MB packed W fragments

    prep_w<<<64, 256, 0, stream>>>(W, P);
    stitch_kernel<<<512, 256, 0, stream>>>(x, P, bias, out);
}

// Round 6
// 112.796 us; speedup vs baseline: 1.3293x; 1.2336x over previous
//
#include <hip/hip_runtime.h>
#include <hip/hip_bf16.h>

// LinearStitcher, round 6: max-TLP single-shot blocks.
// x: [16384, 4096] f32, W: [16,128,256] f32, b: [16,128] f32.
// out[:, a*128+c] = sum_k x[:, a*256+k]*W[a,c,k] + b[a,c];  out[:, 2048:] = 0.
//
// Hypothesis: prior rounds were MLP-starved (2-3 blocks/CU, phase barriers).
// Here: 8192 small blocks (32 rows x 1 area), 16KB LDS, one barrier, one
// f32x16 acc per wave, VGPR-capped for >=6 blocks/CU. Latency hidden by TLP.

typedef __attribute__((ext_vector_type(8))) short bf16x8;
typedef __attribute__((ext_vector_type(16))) float f32x16;

static constexpr int NX   = 4096;
static constexpr int OW   = 4096;
static constexpr int KDIM = 256;
static constexpr int CCH  = 128;

// P[a][ks(16)][n(4)][lane(64)] : 16B slot, exact 32x32x16 B-fragment layout
__global__ __launch_bounds__(256)
void prep_w(const float* __restrict__ W, __hip_bfloat16* __restrict__ P) {
    const int t = blockIdx.x * 256 + threadIdx.x;     // 64 blocks
    for (int s = t; s < 65536; s += 16384) {
        const int a  = s >> 12;
        const int w  = s & 4095;
        const int ks = w >> 8;
        const int n  = (w >> 6) & 3;
        const int l  = w & 63;
        const int ch = n * 32 + (l & 31);
        const int k0 = ks * 16 + (l >> 5) * 8;
        const float* src = W + ((long)a * CCH + ch) * KDIM + k0;
        const float4 w0 = *(const float4*)(src);
        const float4 w1 = *(const float4*)(src + 4);
        union { bf16x8 v; __hip_bfloat162 h[4]; } pw;
        pw.h[0] = __float22bfloat162_rn(make_float2(w0.x, w0.y));
        pw.h[1] = __float22bfloat162_rn(make_float2(w0.z, w0.w));
        pw.h[2] = __float22bfloat162_rn(make_float2(w1.x, w1.y));
        pw.h[3] = __float22bfloat162_rn(make_float2(w1.z, w1.w));
        *(bf16x8*)((char*)P + ((long)s << 4)) = pw.v;
    }
}

__global__ __launch_bounds__(256, 6)
void stitch_kernel(const float* __restrict__ x,
                   const __hip_bfloat16* __restrict__ Pw,
                   const float* __restrict__ bias,
                   float* __restrict__ out) {
    const int tid  = threadIdx.x;
    const int lane = tid & 63;
    const int wid  = tid >> 6;
    const int bid  = blockIdx.x;
    const int area = bid & 15;                 // fastest: 16 blocks share 512KB x region
    const int rowbase = (bid >> 4) * 32;

    __shared__ char As[32 * 512];              // [32 rows][256 k] bf16, 16 KB

    // 1) issue staging loads: wave-instr i reads the FULL 1KB row segment of
    //    row (wid + 4i): 64 lanes x 16B contiguous.
    float4 sv[8];
    const float* xb = x + (long)rowbase * NX + area * KDIM + (lane << 2);
#pragma unroll
    for (int i = 0; i < 8; ++i)
        sv[i] = *(const float4*)(xb + (long)(wid + (i << 2)) * NX);

    // 2) zero mirror half (independent stores, overlap the load latency):
    //    rows rowbase..+32, cols 2048+area*128..+128
    {
        float4* o4 = (float4*)out + 512 + area * (CCH / 4);
        const float4 z = {0.f, 0.f, 0.f, 0.f};
#pragma unroll
        for (int i = 0; i < 4; ++i) {
            const int idx = i * 256 + tid;     // 32 rows x 32 float4
            const int r = idx >> 5, g = idx & 31;
            o4[(long)(rowbase + r) * (OW / 4) + g] = z;
        }
    }

    // 3) convert + LDS write (8B per lane, conflict-free; XOR-swizzled slots)
    const int slotl   = lane >> 1;
    const int halfoff = (lane & 1) << 3;
#pragma unroll
    for (int i = 0; i < 8; ++i) {
        const int r = wid + (i << 2);
        union { unsigned long long u; __hip_bfloat162 h[2]; } pw;
        pw.h[0] = __float22bfloat162_rn(make_float2(sv[i].x, sv[i].y));
        pw.h[1] = __float22bfloat162_rn(make_float2(sv[i].z, sv[i].w));
        *(unsigned long long*)(&As[(r << 9) + ((slotl ^ (r & 7)) << 4) + halfoff]) = pw.u;
    }
    __syncthreads();

    // 4) K-loop: wave `wid` computes the 32x32 quadrant n=wid of this area.
    const int row = lane & 31;
    const int kh  = lane >> 5;
    const bf16x8* bpa = (const bf16x8*)Pw + (long)area * 4096 + wid * 64 + lane;

    f32x16 acc;
#pragma unroll
    for (int r = 0; r < 16; ++r) acc[r] = 0.f;

#pragma unroll
    for (int ks = 0; ks < 16; ++ks) {
        const int slot = (ks << 1) + kh;
        const bf16x8 af = *(const bf16x8*)(&As[(row << 9) + ((slot ^ (row & 7)) << 4)]);
        const bf16x8 bf = bpa[ks << 8];
        acc = __builtin_amdgcn_mfma_f32_32x32x16_bf16(af, bf, acc, 0, 0, 0);
    }

    // 5) epilogue: C/D col = lane&31, row = (reg&3) + 8*(reg>>2) + 4*(lane>>5)
    const int gcol = area * CCH + wid * 32 + row;
    const float bv = bias[gcol];
    const long rb = rowbase + 4 * kh;
#pragma unroll
    for (int r = 0; r < 16; ++r) {
        const long grow = rb + (r & 3) + ((r >> 2) << 3);
        out[grow * OW + gcol] = acc[r] + bv;
    }
}

extern "C" void kernel_launch(void* const* d_in, const int* in_sizes, int n_in,
                              void* d_out, int out_size, void* d_ws, size_t ws_size,
                              hipStream_t stream) {
    const float* x    = (const float*)d_in[0];
    const float* W    = (const float*)d_in[1];
    const float* bias = (const float*)d_in[2];
    float* out = (float*)d_out;
    __hip_bfloat16* P = (__hip_bfloat16*)d_ws;   // 1 MB packed W fragments

    prep_w<<<64, 256, 0, stream>>>(W, P);
    stitch_kernel<<<8192, 256, 0, stream>>>(x, P, bias, out);
}

// Round 8
// 109.959 us; speedup vs baseline: 1.3636x; 1.0258x over previous
//
#include <hip/hip_runtime.h>
#include <hip/hip_bf16.h>

// LinearStitcher, round 8 (= r7 with compile fix): max-TLP + nt streaming.
// x: [16384, 4096] f32, W: [16,128,256] f32, b: [16,128] f32.
// out[:, a*128+c] = sum_k x[:, a*256+k]*W[a,c,k] + b[a,c];  out[:, 2048:] = 0.
//
// __builtin_nontemporal_* requires native vector types -> use ext_vector f32x4
// instead of HIP's float4 struct for all nt-accessed memory.

typedef __attribute__((ext_vector_type(8))) short bf16x8;
typedef __attribute__((ext_vector_type(16))) float f32x16;
typedef __attribute__((ext_vector_type(4)))  float f32x4;

static constexpr int NX   = 4096;
static constexpr int OW   = 4096;
static constexpr int KDIM = 256;
static constexpr int CCH  = 128;

// P[a][ks(16)][n(4)][lane(64)] : 16B slot, exact 32x32x16 B-fragment layout
__global__ __launch_bounds__(256)
void prep_w(const float* __restrict__ W, __hip_bfloat16* __restrict__ P) {
    const int s = blockIdx.x * 256 + threadIdx.x;     // 256 blocks, 1 slot/thread
    const int a  = s >> 12;
    const int w  = s & 4095;
    const int ks = w >> 8;
    const int n  = (w >> 6) & 3;
    const int l  = w & 63;
    const int ch = n * 32 + (l & 31);
    const int k0 = ks * 16 + (l >> 5) * 8;
    const float* src = W + ((long)a * CCH + ch) * KDIM + k0;
    const f32x4 w0 = *(const f32x4*)(src);
    const f32x4 w1 = *(const f32x4*)(src + 4);
    union { bf16x8 v; __hip_bfloat162 h[4]; } pw;
    pw.h[0] = __float22bfloat162_rn(make_float2(w0.x, w0.y));
    pw.h[1] = __float22bfloat162_rn(make_float2(w0.z, w0.w));
    pw.h[2] = __float22bfloat162_rn(make_float2(w1.x, w1.y));
    pw.h[3] = __float22bfloat162_rn(make_float2(w1.z, w1.w));
    *(bf16x8*)((char*)P + ((long)s << 4)) = pw.v;
}

__global__ __launch_bounds__(256, 8)
void stitch_kernel(const float* __restrict__ x,
                   const __hip_bfloat16* __restrict__ Pw,
                   const float* __restrict__ bias,
                   float* __restrict__ out) {
    const int tid  = threadIdx.x;
    const int lane = tid & 63;
    const int wid  = tid >> 6;
    const int bid  = blockIdx.x;
    const int area = bid & 15;                 // same-area blocks -> same XCD
    const int rowbase = (bid >> 4) * 32;

    __shared__ char As[32 * 512];              // [32 rows][256 k] bf16, 16 KB

    const float* xb = x + (long)rowbase * NX + area * KDIM + (lane << 2);
    const int slotl   = lane >> 1;
    const int halfoff = (lane & 1) << 3;

    // batch 0: rows wid + 4i (i=0..3), nt loads (pure streaming)
    f32x4 sv[4];
#pragma unroll
    for (int i = 0; i < 4; ++i)
        sv[i] = __builtin_nontemporal_load(
            (const f32x4*)(xb + (long)(wid + (i << 2)) * NX));

    // zero mirror half (nt stores, overlap load latency):
    // rows rowbase..+32, cols 2048+area*128..+128
    {
        f32x4* o4 = (f32x4*)out + 512 + area * (CCH / 4);
        const f32x4 z = {0.f, 0.f, 0.f, 0.f};
#pragma unroll
        for (int i = 0; i < 4; ++i) {
            const int idx = i * 256 + tid;     // 32 rows x 32 f32x4
            const int r = idx >> 5, g = idx & 31;
            __builtin_nontemporal_store(z, o4 + (long)(rowbase + r) * (OW / 4) + g);
        }
    }

#pragma unroll
    for (int i = 0; i < 4; ++i) {
        const int r = wid + (i << 2);
        union { unsigned long long u; __hip_bfloat162 h[2]; } pw;
        pw.h[0] = __float22bfloat162_rn(make_float2(sv[i].x, sv[i].y));
        pw.h[1] = __float22bfloat162_rn(make_float2(sv[i].z, sv[i].w));
        *(unsigned long long*)(&As[(r << 9) + ((slotl ^ (r & 7)) << 4) + halfoff]) = pw.u;
    }

    // batch 1: rows wid + 16 + 4i
#pragma unroll
    for (int i = 0; i < 4; ++i)
        sv[i] = __builtin_nontemporal_load(
            (const f32x4*)(xb + (long)(wid + 16 + (i << 2)) * NX));
#pragma unroll
    for (int i = 0; i < 4; ++i) {
        const int r = wid + 16 + (i << 2);
        union { unsigned long long u; __hip_bfloat162 h[2]; } pw;
        pw.h[0] = __float22bfloat162_rn(make_float2(sv[i].x, sv[i].y));
        pw.h[1] = __float22bfloat162_rn(make_float2(sv[i].z, sv[i].w));
        *(unsigned long long*)(&As[(r << 9) + ((slotl ^ (r & 7)) << 4) + halfoff]) = pw.u;
    }
    __syncthreads();

    // K-loop: wave `wid` computes the 32x32 quadrant n=wid of this area.
    const int row = lane & 31;
    const int kh  = lane >> 5;
    const bf16x8* bpa = (const bf16x8*)Pw + (long)area * 4096 + wid * 64 + lane;

    f32x16 acc;
#pragma unroll
    for (int r = 0; r < 16; ++r) acc[r] = 0.f;

#pragma unroll
    for (int ks = 0; ks < 16; ++ks) {
        const int slot = (ks << 1) + kh;
        const bf16x8 af = *(const bf16x8*)(&As[(row << 9) + ((slot ^ (row & 7)) << 4)]);
        const bf16x8 bf = bpa[ks << 8];        // cached: W-pack stays L2-hot
        acc = __builtin_amdgcn_mfma_f32_32x32x16_bf16(af, bf, acc, 0, 0, 0);
    }

    // epilogue: C/D col = lane&31, row = (reg&3) + 8*(reg>>2) + 4*(lane>>5)
    const int gcol = area * CCH + wid * 32 + row;
    const float bv = bias[gcol];
    const long rb = rowbase + 4 * kh;
#pragma unroll
    for (int r = 0; r < 16; ++r) {
        const long grow = rb + (r & 3) + ((r >> 2) << 3);
        __builtin_nontemporal_store(acc[r] + bv, out + grow * OW + gcol);
    }
}

extern "C" void kernel_launch(void* const* d_in, const int* in_sizes, int n_in,
                              void* d_out, int out_size, void* d_ws, size_t ws_size,
                              hipStream_t stream) {
    const float* x    = (const float*)d_in[0];
    const float* W    = (const float*)d_in[1];
    const float* bias = (const float*)d_in[2];
    float* out = (float*)d_out;
    __hip_bfloat16* P = (__hip_bfloat16*)d_ws;   // 1 MB packed W fragments

    prep_w<<<256, 256, 0, stream>>>(W, P);
    stitch_kernel<<<8192, 256, 0, stream>>>(x, P, bias, out);
}